// Round 4
// baseline (126.022 us; speedup 1.0000x reference)
//
#include <hip/hip_runtime.h>
#include <math.h>

typedef float f32x4 __attribute__((ext_vector_type(4)));
typedef int   i32x4 __attribute__((ext_vector_type(4)));
typedef int   i32x8 __attribute__((ext_vector_type(8)));
typedef float f32x2 __attribute__((ext_vector_type(2)));

#define MTOT 16384
#define HALF 8192
#define KDIM 256                  /* bytes per row in fp8 Z */
#define BM 256                    /* tile edge */
#define NB (MTOT / BM)            /* 64 block-rows */
#define NBLK (NB * (NB + 1) / 2)  /* 2080 upper-triangle tiles */
#define NBLOCKS 256               /* persistent: 1 block per CU */
#define TPX (NBLK / 8)            /* 260 tiles per XCD */

#define GLDS16(g, l) __builtin_amdgcn_global_load_lds(                      \
    (const __attribute__((address_space(1))) void*)(g),                     \
    (__attribute__((address_space(3))) void*)(l), 16, 0, 0)

/* raw barrier: does NOT drain vmcnt (that is the whole point) */
#define BAR() do { asm volatile("" ::: "memory");                           \
  __builtin_amdgcn_s_barrier(); asm volatile("" ::: "memory"); } while (0)

// ---------------------------------------------------------------------------
// Pass 1: fp32 -> fp8 e4m3 via HW cvt_pk; row norms from the QUANTIZED
// values so the kernel-matrix diagonal cancels exactly. x2 is stored
// PRE-SCALED by -0.5 (it is only ever consumed that way). Also zero-inits
// the fused-reduce accumulator + completion counter.
// ---------------------------------------------------------------------------
__global__ __launch_bounds__(256) void convert_kernel(
    const float* __restrict__ Nmat, const float* __restrict__ Rmat,
    unsigned int* __restrict__ Z, float* __restrict__ x2,
    float* __restrict__ accum, unsigned int* __restrict__ counter) {
  if (blockIdx.x == 0 && threadIdx.x == 0) { *accum = 0.f; *counter = 0u; }
  const int lane = threadIdx.x & 63;
  const int wv = threadIdx.x >> 6;
  const int row = blockIdx.x * 4 + wv;          // 0..16383
  const float* src = (row < HALF) ? (Nmat + (size_t)row * KDIM)
                                  : (Rmat + (size_t)(row - HALF) * KDIM);
  float4 v = *(const float4*)(src + lane * 4);
  int pk = __builtin_amdgcn_cvt_pk_fp8_f32(v.x, v.y, 0, false);
  pk = __builtin_amdgcn_cvt_pk_fp8_f32(v.z, v.w, pk, true);
  Z[(size_t)row * (KDIM / 4) + lane] = (unsigned int)pk;
  f32x2 d01 = __builtin_amdgcn_cvt_pk_f32_fp8(pk, false);
  f32x2 d23 = __builtin_amdgcn_cvt_pk_f32_fp8(pk, true);
  float sq = d01[0] * d01[0] + d01[1] * d01[1] + d23[0] * d23[0] + d23[1] * d23[1];
  #pragma unroll
  for (int off = 32; off; off >>= 1) sq += __shfl_down(sq, off);
  if (lane == 0) x2[row] = -0.5f * sq;
}

__device__ __forceinline__ void decode_tile(int t, int& bm, int& bn) {
  const int u = NBLK - 1 - t;
  int rr = (int)((sqrtf(8.0f * (float)u + 1.0f) - 1.0f) * 0.5f);
  while (rr * (rr + 1) / 2 > u) --rr;
  while ((rr + 1) * (rr + 2) / 2 <= u) ++rr;
  bm = NB - 1 - rr;
  bn = bm + (t - (bm * NB - bm * (bm - 1) / 2));
}

// ---------------------------------------------------------------------------
// Pass 2: persistent counted-vmcnt pipeline over the tile stream.
//
// Round-2 bug fixed: ACCINIT's GLOBAL x2 loads were the newest vmem ops,
// so waiting for their data drained the whole GLDS prefetch FIFO every
// tile (pipeline collapsed to stage->drain->compute, MfmaUtil 22%). Now
// x2 rides the GLDS stream into LDS (2 extra ops on even slabs,
// duplicate-written by all 8 waves - identical bytes, benign; each wave
// waits only on ITS OWN copy, so no extra barrier is needed) and ACCINIT
// consumes it via ds_read (lgkmcnt only). The steady-state loop issues NO
// vmem op whose data is consumed in-loop; waits are exactly:
//   loop top, even j : vmcnt(8)   (allowance = slab j+1 in flight)
//   loop top, odd  j : vmcnt(10)  (slab j+1 is even: +2 x2 ops)
//   pre-ACCINIT      : vmcnt(16)  (retire ONLY the 2 oldest = x2 ops;
//                                  all 16 tile-data ops stay in flight)
//   last iteration   : vmcnt(0)
// Per-lane running accumulator across tiles: no in-loop atomics/reduces,
// so every wave's vmem FIFO count is identical by construction.
//
// Round-3 container crash hardening: all LDS buffers explicitly
// __align__(16) -- global_load_lds width=16 requires a 16B-aligned LDS
// destination, and x2h's placement after the slab buffers was only
// 4B-guaranteed before.
//
// LDS swizzle identical to the verified layout: slot s of row r holds
// chunk s ^ (r&7); 8-lane b128 read phases hit all 32 banks.
// ---------------------------------------------------------------------------
__global__ __launch_bounds__(512, 2) void mmd_gemm(
    const unsigned char* __restrict__ Z, const float* __restrict__ x2,
    float* __restrict__ accum, unsigned int* __restrict__ counter,
    float* __restrict__ out) {
  __shared__ __align__(16) unsigned char As[2 * 32768];  // two 32 KB A K-slabs
  __shared__ __align__(16) unsigned char Bs[2 * 32768];  // two 32 KB B K-slabs
  __shared__ __align__(16) float x2h[2][512];  // per-parity [A rows | B cols], pre * -0.5
  __shared__ __align__(16) float wsred[8];

  const int tid  = threadIdx.x;
  const int lane = tid & 63;
  const int wid  = tid >> 6;       // 0..7
  const int wm   = wid >> 2;       // wave row (0..1): 128 output rows
  const int wn   = wid & 3;        // wave col (0..3): 64 output cols

  // staging geometry (swizzle key == row&7 == lane>>3)
  const int lr = lane >> 3;
  const int ls = lane & 7;
  const int cofs = lr * KDIM + ((ls ^ lr) << 4);

  // fragment geometry
  const int fr = lane & 15;
  const int fq = lane >> 4;
  const int key = fr & 7;
  const int slotL = ((2 * fq) ^ key) * 16;
  const int slotH = ((2 * fq + 1) ^ key) * 16;

  const int xcd = blockIdx.x & 7;
  const int lb  = blockIdx.x >> 3;                    // 0..31 within XCD
  const int niter = (lb < (TPX & 31)) ? (TPX / 32 + 1) : (TPX / 32); // 9 or 8
  const int nslab = 2 * niter;

  f32x4 acc[8][4];
  float running = 0.f;

  auto STAGE = [&](int bmv, int bnv, int h, int buf) {   // 8 GLDS16
    const unsigned char* Ab = Z + (size_t)bmv * (BM * KDIM) + h * 128 + cofs;
    const unsigned char* Bb = Z + (size_t)bnv * (BM * KDIM) + h * 128 + cofs;
    unsigned char* Ad = As + buf * 32768;
    unsigned char* Bd = Bs + buf * 32768;
    #pragma unroll
    for (int tt = 0; tt < 4; ++tt) {
      int i = wid * 4 + tt;                 // wave-uniform instruction id
      GLDS16(Ab + i * 2048, Ad + i * 1024);
      GLDS16(Bb + i * 2048, Bd + i * 1024);
    }
  };

  auto STAGEX2 = [&](int bmv, int bnv, int par) {        // 2 GLDS16 (all waves dup)
    GLDS16((const unsigned char*)(x2 + bmv * BM) + lane * 16,
           (unsigned char*)&x2h[par][0]);
    GLDS16((const unsigned char*)(x2 + bnv * BM) + lane * 16,
           (unsigned char*)&x2h[par][256]);
  };

  auto ACCINIT = [&](int par) {                          // LDS-only (lgkmcnt)
    float xch[4];
    #pragma unroll
    for (int tn = 0; tn < 4; ++tn)
      xch[tn] = x2h[par][256 + wn * 64 + tn * 16 + fr];
    #pragma unroll
    for (int tm = 0; tm < 8; ++tm) {
      f32x4 xr = *(const f32x4*)&x2h[par][wm * 128 + tm * 16 + fq * 4];
      #pragma unroll
      for (int tn = 0; tn < 4; ++tn)
        #pragma unroll
        for (int v = 0; v < 4; ++v)
          acc[tm][tn][v] = xr[v] + xch[tn];
    }
  };

  int cbm, cbn;
  decode_tile(xcd * TPX + lb, cbm, cbn);
  int nbm = cbm, nbn = cbn;
  int cpar = 0;

  STAGEX2(cbm, cbn, 0);            // FIFO: [x2(2), A0/B0(8), A1/B1(8)] = 18
  STAGE(cbm, cbn, 0, 0);
  STAGE(cbm, cbn, 1, 1);
  asm volatile("s_waitcnt vmcnt(16)" ::: "memory");   // x2 of tile 0 landed
  ACCINIT(0);

  for (int j = 0; j < nslab; ++j) {
    const int bsel = j & 1;
    if (j + 1 >= nslab)      asm volatile("s_waitcnt vmcnt(0)" ::: "memory");
    else if (bsel == 0)      asm volatile("s_waitcnt vmcnt(8)" ::: "memory");
    else                     asm volatile("s_waitcnt vmcnt(10)" ::: "memory");
    BAR();                                  // slab j readable by all waves

    { // ---- compute slab j from buf[bsel]
      const unsigned char* A_s = As + bsel * 32768;
      const unsigned char* B_s = Bs + bsel * 32768;
      i32x8 bf[4];
      #pragma unroll
      for (int tn = 0; tn < 4; ++tn) {
        int row = wn * 64 + tn * 16 + fr;
        i32x4 lo = *(const i32x4*)(B_s + row * 128 + slotL);
        i32x4 hi = *(const i32x4*)(B_s + row * 128 + slotH);
        bf[tn] = __builtin_shufflevector(lo, hi, 0, 1, 2, 3, 4, 5, 6, 7);
      }
      #pragma unroll
      for (int tm = 0; tm < 8; ++tm) {
        int row = wm * 128 + tm * 16 + fr;
        i32x4 lo = *(const i32x4*)(A_s + row * 128 + slotL);
        i32x4 hi = *(const i32x4*)(A_s + row * 128 + slotH);
        i32x8 af = __builtin_shufflevector(lo, hi, 0, 1, 2, 3, 4, 5, 6, 7);
        #pragma unroll
        for (int tn = 0; tn < 4; ++tn)
          acc[tm][tn] = __builtin_amdgcn_mfma_scale_f32_16x16x128_f8f6f4(
              af, bf[tn], acc[tm][tn], 0, 0,
              0, 0x7F7F7F7F, 0, 0x7F7F7F7F);
      }
    }
    BAR();                                  // all waves done reading buf[bsel]

    if (j + 2 < nslab) {                    // prefetch slab j+2 into buf[bsel]
      if (bsel == 0) {                      // next tile's even half: decode + x2
        decode_tile(xcd * TPX + lb + 32 * ((j >> 1) + 1), nbm, nbn);
        STAGEX2(nbm, nbn, cpar ^ 1);
        STAGE(nbm, nbn, 0, 0);
      } else {
        STAGE(nbm, nbn, 1, 1);
      }
    }

    if (bsel == 1) {
      // ---- epilogue for finished tile (cbm,cbn): acc = -d2/2
      float amax = -1e30f;
      #pragma unroll
      for (int tm = 0; tm < 8; ++tm)
        #pragma unroll
        for (int tn = 0; tn < 4; ++tn) {    // v_max3-friendly: 2 inst / 4 vals
          float m1 = fmaxf(fmaxf(acc[tm][tn][0], acc[tm][tn][1]), acc[tm][tn][2]);
          amax = fmaxf(fmaxf(amax, m1), acc[tm][tn][3]);
        }

      float partial = 0.f;
      if (__any(amax > -40.f)) {            // diagonal tiles + freak near-pairs
        #pragma unroll
        for (int tm = 0; tm < 8; ++tm)
          #pragma unroll
          for (int tn = 0; tn < 4; ++tn)
            #pragma unroll
            for (int v = 0; v < 4; ++v) {
              float a = fminf(acc[tm][tn][v], 0.f);   // clamp d2 >= 0
              partial += exp2f(a * 2.885390082f);     // exp(2a)
            }
      }
      float wgt = ((cbm < NB / 2) == (cbn < NB / 2)) ? 1.f : -1.f;
      if (cbm != cbn) wgt *= 2.f;           // off-diag: symmetry
      running += partial * wgt;             // per-lane, reduced once at end

      if (j + 2 < nslab) {                  // next tile's x2 -> acc re-init
        asm volatile("s_waitcnt vmcnt(16)" ::: "memory");  // retire 2 x2 ops only
        cpar ^= 1;
        ACCINIT(cpar);
        cbm = nbm; cbn = nbn;
      }
    }
  }

  // ---- final reduce: one shfl cascade + one atomic per block
  #pragma unroll
  for (int off = 32; off; off >>= 1) running += __shfl_down(running, off);
  if (lane == 0) wsred[wid] = running;
  __syncthreads();
  if (tid == 0) {
    float bs = 0.f;
    #pragma unroll
    for (int w = 0; w < 8; ++w) bs += wsred[w];
    atomicAdd(accum, bs);
    __threadfence();                        // order adds before counter bump
    unsigned int old = atomicAdd(counter, 1u);
    if (old == NBLOCKS - 1) {               // last block: all adds L2-visible
      float tot = atomicAdd(accum, 0.f);    // coherent RMW read
      float mmd = tot / ((float)HALF * (float)HALF);
      out[0] = sqrtf(fmaxf(mmd, 0.f));
    }
  }
}

extern "C" void kernel_launch(void* const* d_in, const int* in_sizes, int n_in,
                              void* d_out, int out_size, void* d_ws, size_t ws_size,
                              hipStream_t stream) {
  const float* Nmat = (const float*)d_in[0];
  const float* Rmat = (const float*)d_in[1];
  float* out = (float*)d_out;

  char* ws = (char*)d_ws;
  unsigned char* Z = (unsigned char*)ws;                       // 4 MiB
  float* x2        = (float*)(ws + (size_t)MTOT * KDIM);       // 64 KiB
  float* accum     = (float*)(ws + (size_t)MTOT * KDIM + (size_t)MTOT * 4);
  unsigned int* counter = (unsigned int*)(ws + (size_t)MTOT * KDIM + (size_t)MTOT * 4 + 4);

  convert_kernel<<<MTOT / 4, 256, 0, stream>>>(Nmat, Rmat, (unsigned int*)Z, x2,
                                               accum, counter);
  mmd_gemm<<<NBLOCKS, 512, 0, stream>>>(Z, x2, accum, counter, out);
}